// Round 1
// baseline (423.963 us; speedup 1.0000x reference)
//
#include <hip/hip_runtime.h>
#include <hip/hip_bf16.h>
#include <cstdint>
#include <cstddef>

// Problem constants (match reference)
#define TOKENS 8192        // B*S
#define ASSIGN 16384       // TOKENS * TOPK
#define DM     512         // D_MODEL
#define DFF    2048        // D_FF
#define NEXP   64          // NCAT * NSUB
#define NSUB_  8
#define CAP2   512         // per-expert capacity region (counts ~256±16; 512 is 16-sigma safe)

typedef __bf16 bf16;
typedef __bf16 bf16x8 __attribute__((ext_vector_type(8)));
typedef float  f32x4  __attribute__((ext_vector_type(4)));

// ---------------- routing ----------------
__global__ void k_zero(int* __restrict__ count) { count[threadIdx.x] = 0; }

__global__ void k_route(const int* __restrict__ cat, const int* __restrict__ sub,
                        int* __restrict__ count, int* __restrict__ slot_of) {
    int a = blockIdx.x * 256 + threadIdx.x;
    if (a >= ASSIGN) return;
    int e = cat[a] * NSUB_ + sub[a];
    int s = atomicAdd(&count[e], 1);
    // slot order differs from reference cumsum, but output is order-invariant
    // unless an expert exceeds CAP2 (impossible for this distribution).
    slot_of[a] = (s < CAP2) ? (e * CAP2 + s) : -1;
}

// ---------------- gather x -> bf16 capacity buffer ----------------
__global__ void k_gather(const float* __restrict__ hidden, const int* __restrict__ slot_of,
                         bf16* __restrict__ xg) {
    int a = blockIdx.x;
    int r = slot_of[a];
    if (r < 0) return;
    int tok = a >> 1;                 // TOPK = 2
    int t = threadIdx.x;              // 64 threads, 8 elems each
    const float4* src = (const float4*)(hidden + (size_t)tok * DM);
    float4 v0 = src[t * 2], v1 = src[t * 2 + 1];
    bf16x8 o;
    o[0] = (bf16)v0.x; o[1] = (bf16)v0.y; o[2] = (bf16)v0.z; o[3] = (bf16)v0.w;
    o[4] = (bf16)v1.x; o[5] = (bf16)v1.y; o[6] = (bf16)v1.z; o[7] = (bf16)v1.w;
    *(bf16x8*)(xg + (size_t)r * DM + t * 8) = o;
}

// ---------------- transpose + fp32->bf16 convert ----------------
// in: per-expert [R][C] fp32, out: per-expert [C][R] bf16. grid (C/64, R/64, NEXP), 256 thr
__global__ void k_transpose(const float* __restrict__ in, bf16* __restrict__ out, int R, int C) {
    __shared__ float tile[64][65];    // +1 pad: conflict-free column reads
    int e = blockIdx.z;
    const float* src = in + (size_t)e * R * C;
    bf16* dst = out + (size_t)e * R * C;
    int c0 = blockIdx.x * 64, r0 = blockIdx.y * 64;
    int t = threadIdx.x;
#pragma unroll
    for (int p = 0; p < 4; p++) {
        int r = p * 16 + (t >> 4), c = (t & 15) * 4;
        float4 v = *(const float4*)(src + (size_t)(r0 + r) * C + c0 + c);
        tile[r][c] = v.x; tile[r][c + 1] = v.y; tile[r][c + 2] = v.z; tile[r][c + 3] = v.w;
    }
    __syncthreads();
#pragma unroll
    for (int p = 0; p < 2; p++) {
        int cc = p * 32 + (t >> 3), rr = (t & 7) * 8;
        bf16x8 o;
#pragma unroll
        for (int j = 0; j < 8; j++) o[j] = (bf16)tile[rr + j][cc];
        *(bf16x8*)(dst + (size_t)(c0 + cc) * R + r0 + rr) = o;
    }
}

// ---------------- GEMM (m97-style 128x128 tile, BK=64, global_load_lds + T2 swizzle) ----
__device__ inline void gload_lds16(const void* g, void* l) {
    __builtin_amdgcn_global_load_lds((const __attribute__((address_space(1))) void*)g,
                                     (__attribute__((address_space(3))) void*)l, 16, 0, 0);
}

// A: [NEXP*CAP2][K] bf16 row-major (K-contig). B: [NEXP*N][K] bf16 row-major (K-contig).
// C: [NEXP*CAP2][N] bf16. bias: [NEXP*N] fp32. Computes C = act(A*B^T + bias) on rows < count[e].
template <bool GELU>
__global__ __launch_bounds__(256) void k_gemm(const bf16* __restrict__ A,
                                              const bf16* __restrict__ B,
                                              const float* __restrict__ bias,
                                              bf16* __restrict__ C,
                                              const int* __restrict__ count, int N, int K) {
    __shared__ __align__(16) char As[16384];   // 128 rows x 64 cols bf16 (XOR-swizzled)
    __shared__ __align__(16) char Bs[16384];
    int e = blockIdx.z, mtile = blockIdx.y, ntile = blockIdx.x;
    int mc = count[e]; if (mc > CAP2) mc = CAP2;
    if (mtile * 128 >= mc) return;             // dead M-tile
    int tid = threadIdx.x, wave = tid >> 6, lane = tid & 63;
    int wm = wave >> 1, wn = wave & 1;         // 2x2 waves, 64x64 each

    const char* Agbase = (const char*)(A + (size_t)(e * CAP2 + mtile * 128) * K);
    const char* Bgbase = (const char*)(B + (size_t)(e * N + ntile * 128) * K);

    f32x4 acc[4][4];
#pragma unroll
    for (int i = 0; i < 4; i++)
#pragma unroll
        for (int j = 0; j < 4; j++) acc[i][j] = f32x4{0.f, 0.f, 0.f, 0.f};

    int nK = K >> 6;
    for (int kt = 0; kt < nK; kt++) {
        __syncthreads();                       // previous iter's LDS reads done
        // stage both tiles: 16 chunks of 1024B each; dest linear, source pre-swizzled
        // (rule #21: global_load_lds writes linearly; swizzle source + swizzle reads)
#pragma unroll
        for (int i = 0; i < 4; i++) {
            int chunk = i * 4 + wave;
            int d = chunk * 1024 + lane * 16;  // dest byte
            int row = d >> 7;                  // 128 B per row
            int colb = (d & 127) ^ ((row & 7) << 4);
            size_t goff = (size_t)row * (K * 2) + (size_t)kt * 128 + colb;
            gload_lds16(Agbase + goff, As + chunk * 1024);
            gload_lds16(Bgbase + goff, Bs + chunk * 1024);
        }
        asm volatile("s_waitcnt vmcnt(0)" ::: "memory");
        __syncthreads();
#pragma unroll
        for (int ks = 0; ks < 2; ks++) {
            bf16x8 af[4], bfr[4];
#pragma unroll
            for (int mi = 0; mi < 4; mi++) {
                int row = wm * 64 + mi * 16 + (lane & 15);
                int byt = row * 128 + ((ks * 64 + (lane >> 4) * 16) ^ ((row & 7) << 4));
                af[mi] = *(const bf16x8*)(As + byt);
            }
#pragma unroll
            for (int ni = 0; ni < 4; ni++) {
                int row = wn * 64 + ni * 16 + (lane & 15);
                int byt = row * 128 + ((ks * 64 + (lane >> 4) * 16) ^ ((row & 7) << 4));
                bfr[ni] = *(const bf16x8*)(Bs + byt);
            }
#pragma unroll
            for (int mi = 0; mi < 4; mi++)
#pragma unroll
                for (int ni = 0; ni < 4; ni++)
                    acc[mi][ni] = __builtin_amdgcn_mfma_f32_16x16x32_bf16(
                        af[mi], bfr[ni], acc[mi][ni], 0, 0, 0);
        }
    }

    // epilogue: bias + (optional) exact GELU, write bf16
#pragma unroll
    for (int mi = 0; mi < 4; mi++) {
        int rowb = wm * 64 + mi * 16 + ((lane >> 4) << 2);
#pragma unroll
        for (int ni = 0; ni < 4; ni++) {
            int col = ntile * 128 + wn * 64 + ni * 16 + (lane & 15);
            float bv = bias[e * N + col];
#pragma unroll
            for (int r = 0; r < 4; r++) {
                float v = acc[mi][ni][r] + bv;
                if (GELU) v = 0.5f * v * (1.0f + erff(v * 0.70710678118654752f));
                int grow = e * CAP2 + mtile * 128 + rowb + r;
                C[(size_t)grow * N + col] = (bf16)v;
            }
        }
    }
}

// ---------------- combine ----------------
__global__ void k_combine(const float* __restrict__ wts, const int* __restrict__ slot_of,
                          const bf16* __restrict__ y, float* __restrict__ out) {
    int tok = blockIdx.x, t = threadIdx.x;   // 64 threads, 8 elems each
    float acc[8] = {0, 0, 0, 0, 0, 0, 0, 0};
#pragma unroll
    for (int k = 0; k < 2; k++) {
        int a = tok * 2 + k;
        int r = slot_of[a];
        if (r >= 0) {
            float w = wts[a];
            bf16x8 v = *(const bf16x8*)(y + (size_t)r * DM + t * 8);
#pragma unroll
            for (int j = 0; j < 8; j++) acc[j] += w * (float)v[j];
        }
    }
    float4* o = (float4*)(out + (size_t)tok * DM + t * 8);
    o[0] = make_float4(acc[0], acc[1], acc[2], acc[3]);
    o[1] = make_float4(acc[4], acc[5], acc[6], acc[7]);
}

// ---------------- launch ----------------
extern "C" void kernel_launch(void* const* d_in, const int* in_sizes, int n_in,
                              void* d_out, int out_size, void* d_ws, size_t ws_size,
                              hipStream_t stream) {
    const float* hidden = (const float*)d_in[0];
    const int*   cat    = (const int*)d_in[1];
    const int*   sub    = (const int*)d_in[2];
    const float* wts    = (const float*)d_in[3];
    const float* W1     = (const float*)d_in[4];
    const float* b1     = (const float*)d_in[5];
    const float* W2     = (const float*)d_in[6];
    const float* b2     = (const float*)d_in[7];
    float* out = (float*)d_out;

    // workspace layout (~302.3 MB):
    //   Wt   : shared region for W1t then W2t (transposed bf16)  134.2 MB
    //   hbuf : GELU activations bf16 [NEXP*CAP2][DFF]            134.2 MB
    //   xg/y : aliased bf16 [NEXP*CAP2][{DM}]                     33.6 MB
    //   count/slot_of                                             ~66 KB
    char* ws = (char*)d_ws;
    size_t off = 0;
    bf16* Wt   = (bf16*)(ws + off); off += (size_t)NEXP * DM * DFF * 2;
    bf16* hbuf = (bf16*)(ws + off); off += (size_t)NEXP * CAP2 * DFF * 2;
    bf16* xg   = (bf16*)(ws + off); off += (size_t)NEXP * CAP2 * DM * 2;
    bf16* y    = xg;  // xg dead after GEMM1; GEMM2 writes y here (stream-ordered)
    int* count   = (int*)(ws + off); off += 256;
    int* slot_of = (int*)(ws + off); off += (size_t)ASSIGN * 4;

    k_zero<<<1, 64, 0, stream>>>(count);
    k_route<<<ASSIGN / 256, 256, 0, stream>>>(cat, sub, count, slot_of);

    // W1 [e][512][2048] -> Wt [e][2048][512] bf16
    dim3 g1(DFF / 64, DM / 64, NEXP);
    k_transpose<<<g1, 256, 0, stream>>>(W1, Wt, DM, DFF);

    k_gather<<<ASSIGN, 64, 0, stream>>>(hidden, slot_of, xg);

    // h = gelu(x @ W1 + b1): M=count[e], N=2048, K=512
    dim3 gg1(DFF / 128, CAP2 / 128, NEXP);
    k_gemm<true><<<gg1, 256, 0, stream>>>(xg, Wt, b1, hbuf, count, DFF, DM);

    // W2 [e][2048][512] -> Wt [e][512][2048] bf16 (reuses Wt region)
    dim3 g2(DM / 64, DFF / 64, NEXP);
    k_transpose<<<g2, 256, 0, stream>>>(W2, Wt, DFF, DM);

    // y = h @ W2 + b2: M=count[e], N=512, K=2048
    dim3 gg2(DM / 128, CAP2 / 128, NEXP);
    k_gemm<false><<<gg2, 256, 0, stream>>>(hbuf, Wt, b2, y, count, DM, DFF);

    k_combine<<<TOKENS, 64, 0, stream>>>(wts, slot_of, y, out);
}

// Round 2
// 347.226 us; speedup vs baseline: 1.2210x; 1.2210x over previous
//
#include <hip/hip_runtime.h>
#include <hip/hip_bf16.h>
#include <cstdint>
#include <cstddef>

// Problem constants (match reference)
#define TOKENS 8192        // B*S
#define ASSIGN 16384       // TOKENS * TOPK
#define DM     512         // D_MODEL
#define DFF    2048        // D_FF
#define NEXP   64          // NCAT * NSUB
#define NSUB_  8
#define CAP2   512         // per-expert capacity region (counts ~256 +/- 16)

// GEMM tile
#define BM 256
#define BN 128
#define BK 64

typedef __bf16 bf16;
typedef __bf16 bf16x4 __attribute__((ext_vector_type(4)));
typedef __bf16 bf16x8 __attribute__((ext_vector_type(8)));
typedef float  f32x4  __attribute__((ext_vector_type(4)));

// ---------------- routing ----------------
__global__ void k_zero(int* __restrict__ count) { count[threadIdx.x] = 0; }

__global__ void k_route(const int* __restrict__ cat, const int* __restrict__ sub,
                        int* __restrict__ count, int* __restrict__ slot_of) {
    int a = blockIdx.x * 256 + threadIdx.x;
    if (a >= ASSIGN) return;
    int e = cat[a] * NSUB_ + sub[a];
    int s = atomicAdd(&count[e], 1);
    // slot order differs from reference cumsum; output is order-invariant
    // (no expert can exceed CAP2=512 for this distribution: 256 +/- 16sigma).
    slot_of[a] = (s < CAP2) ? (e * CAP2 + s) : -1;
}

// ---------------- gather x -> bf16 capacity buffer ----------------
__global__ void k_gather(const float* __restrict__ hidden, const int* __restrict__ slot_of,
                         bf16* __restrict__ xg) {
    int a = blockIdx.x;
    int r = slot_of[a];
    if (r < 0) return;
    int tok = a >> 1;                 // TOPK = 2
    int t = threadIdx.x;              // 64 threads, 8 elems each
    const f32x4* src = (const f32x4*)(hidden + (size_t)tok * DM);
    f32x4 v0 = src[t * 2], v1 = src[t * 2 + 1];
    bf16x8 o;
    o[0] = (bf16)v0[0]; o[1] = (bf16)v0[1]; o[2] = (bf16)v0[2]; o[3] = (bf16)v0[3];
    o[4] = (bf16)v1[0]; o[5] = (bf16)v1[1]; o[6] = (bf16)v1[2]; o[7] = (bf16)v1[3];
    *(bf16x8*)(xg + (size_t)r * DM + t * 8) = o;
}

// ---------------- fused GEMM with in-staging W transpose+convert ----------------
__device__ inline void gload_lds16(const void* g, void* l) {
    __builtin_amdgcn_global_load_lds((const __attribute__((address_space(1))) void*)g,
                                     (__attribute__((address_space(3))) void*)l, 16, 0, 0);
}

// A: [NEXP*CAP2][K] bf16 row-major (K-contig), staged via global_load_lds + T2 swizzle.
// W: [NEXP][K][N] fp32 (natural layout) -> reg-staged transpose+convert to LDS [BN][BK] bf16.
// C: [NEXP*CAP2][N] bf16 = act(A*W + bias), rows < count[e] meaningful.
template <bool GELU>
__global__ __launch_bounds__(512) void k_gemm(const bf16* __restrict__ A,
                                              const float* __restrict__ W,
                                              const float* __restrict__ bias,
                                              bf16* __restrict__ C,
                                              const int* __restrict__ count, int N, int K) {
    __shared__ __align__(16) char As0[BM * BK * 2];   // 32 KB
    __shared__ __align__(16) char As1[BM * BK * 2];   // 32 KB (double buffer)
    __shared__ __align__(16) char Bs[BN * BK * 2];    // 16 KB

    int e = blockIdx.z, mtile = blockIdx.y, ntile = blockIdx.x;
    int mc = count[e]; if (mc > CAP2) mc = CAP2;
    if (mtile * BM >= mc) return;                     // dead M-tile
    int tid = threadIdx.x, wave = tid >> 6, lane = tid & 63;
    int wm = wave >> 1, wn = wave & 1;                // 4x2 waves, 64x64 out each

    const char*  Ag = (const char*)(A + (size_t)(e * CAP2 + mtile * BM) * K);
    const float* Wg = W + (size_t)e * K * N + (size_t)ntile * BN;

    // B-staging lane mapping: kq in [0,16) (k-group of 4), nq in [0,32) (n-group of 4).
    // Bits: kq = lane[3:6) | wave[0]; nq = lane[0:3) | wave[1:3).  Bijective over 512 thr.
    // Per global-load inst: 8 rows x 128B contiguous.  Per ds_write_b64 inst: 16 8B-slots
    // x 4 lanes each (optimal for 64x8B).
    int kq = ((lane >> 3) & 7) | ((wave & 1) << 3);
    int nq = (lane & 7) | (((wave >> 1) & 3) << 3);

    f32x4 br[4];  // one in-flight W sub-tile: 4 k-rows x 4 n  (single set: rule #20)

    auto issueB = [&](int kt) {
        const float* p = Wg + (size_t)(kt * BK + kq * 4) * N + nq * 4;
        br[0] = *(const f32x4*)(p);
        br[1] = *(const f32x4*)(p + N);
        br[2] = *(const f32x4*)(p + 2 * (size_t)N);
        br[3] = *(const f32x4*)(p + 3 * (size_t)N);
    };
    auto issueA = [&](int kt, char* dst) {
#pragma unroll
        for (int i = 0; i < 4; i++) {
            int chunk = i * 8 + wave;
            int d = chunk * 1024 + lane * 16;         // linear dest byte
            int row = d >> 7;                         // 128 B per LDS row
            int col = (d & 127) ^ ((row & 7) << 4);   // pre-swizzled SOURCE (rule #21)
            gload_lds16(Ag + (size_t)row * (2 * K) + (size_t)kt * 128 + col,
                        dst + chunk * 1024);
        }
    };
    auto writeB = [&]() {                             // transpose in regs -> swizzled LDS
#pragma unroll
        for (int c = 0; c < 4; c++) {
            int n = nq * 4 + c;
            bf16x4 v;
#pragma unroll
            for (int j = 0; j < 4; j++) v[j] = (bf16)br[j][c];
            *(bf16x4*)(Bs + n * 128 + ((kq * 8) ^ ((n & 7) << 4))) = v;
        }
    };

    f32x4 acc[4][4];
#pragma unroll
    for (int i = 0; i < 4; i++)
#pragma unroll
        for (int j = 0; j < 4; j++) acc[i][j] = f32x4{0.f, 0.f, 0.f, 0.f};

    auto mfmaTile = [&](const char* Ab) {
#pragma unroll
        for (int ks = 0; ks < 2; ks++) {
            bf16x8 af[4], bfv[4];
#pragma unroll
            for (int mi = 0; mi < 4; mi++) {
                int row = wm * 64 + mi * 16 + (lane & 15);
                af[mi] = *(const bf16x8*)(Ab + row * 128 +
                         ((ks * 64 + (lane >> 4) * 16) ^ ((row & 7) << 4)));
            }
#pragma unroll
            for (int ni = 0; ni < 4; ni++) {
                int row = wn * 64 + ni * 16 + (lane & 15);
                bfv[ni] = *(const bf16x8*)(Bs + row * 128 +
                          ((ks * 64 + (lane >> 4) * 16) ^ ((row & 7) << 4)));
            }
#pragma unroll
            for (int mi = 0; mi < 4; mi++)
#pragma unroll
                for (int ni = 0; ni < 4; ni++)
                    acc[mi][ni] = __builtin_amdgcn_mfma_f32_16x16x32_bf16(
                        af[mi], bfv[ni], acc[mi][ni], 0, 0, 0);
        }
    };

    // prologue: stage tile 0
    issueA(0, As0);
    issueB(0);
    asm volatile("s_waitcnt vmcnt(0)" ::: "memory");
    __syncthreads();
    writeB();
    __syncthreads();

    char* Acur = As0; char* Anx = As1;
    int nK = K >> 6;
    for (int kt = 0; kt < nK; kt++) {
        int nxt = (kt + 1 < nK) ? kt + 1 : kt;        // clamped prefetch (last iter harmless)
        issueA(nxt, Anx);                              // in flight across MFMA phase
        issueB(nxt);
        mfmaTile(Acur);
        asm volatile("s_waitcnt vmcnt(0)" ::: "memory");
        __syncthreads();                               // all waves done reading Bs
        writeB();                                      // B(t+1) -> Bs
        __syncthreads();
        char* t = Acur; Acur = Anx; Anx = t;
    }

    // epilogue: bias + (optional) exact GELU, write bf16
#pragma unroll
    for (int mi = 0; mi < 4; mi++) {
        int rowb = wm * 64 + mi * 16 + ((lane >> 4) << 2);
#pragma unroll
        for (int ni = 0; ni < 4; ni++) {
            int col = ntile * BN + wn * 64 + ni * 16 + (lane & 15);
            float bv = bias[e * N + col];
#pragma unroll
            for (int r = 0; r < 4; r++) {
                float v = acc[mi][ni][r] + bv;
                if (GELU) v = 0.5f * v * (1.0f + erff(v * 0.70710678118654752f));
                int grow = e * CAP2 + mtile * BM + rowb + r;
                C[(size_t)grow * N + col] = (bf16)v;
            }
        }
    }
}

// ---------------- combine ----------------
__global__ void k_combine(const float* __restrict__ wts, const int* __restrict__ slot_of,
                          const bf16* __restrict__ y, float* __restrict__ out) {
    int tok = blockIdx.x, t = threadIdx.x;   // 64 threads, 8 elems each
    float acc[8] = {0, 0, 0, 0, 0, 0, 0, 0};
#pragma unroll
    for (int k = 0; k < 2; k++) {
        int a = tok * 2 + k;
        int r = slot_of[a];
        if (r >= 0) {
            float w = wts[a];
            bf16x8 v = *(const bf16x8*)(y + (size_t)r * DM + t * 8);
#pragma unroll
            for (int j = 0; j < 8; j++) acc[j] += w * (float)v[j];
        }
    }
    f32x4* o = (f32x4*)(out + (size_t)tok * DM + t * 8);
    o[0] = f32x4{acc[0], acc[1], acc[2], acc[3]};
    o[1] = f32x4{acc[4], acc[5], acc[6], acc[7]};
}

// ---------------- launch ----------------
extern "C" void kernel_launch(void* const* d_in, const int* in_sizes, int n_in,
                              void* d_out, int out_size, void* d_ws, size_t ws_size,
                              hipStream_t stream) {
    const float* hidden = (const float*)d_in[0];
    const int*   cat    = (const int*)d_in[1];
    const int*   sub    = (const int*)d_in[2];
    const float* wts    = (const float*)d_in[3];
    const float* W1     = (const float*)d_in[4];
    const float* b1     = (const float*)d_in[5];
    const float* W2     = (const float*)d_in[6];
    const float* b2     = (const float*)d_in[7];
    float* out = (float*)d_out;

    // workspace (~168 MB): hbuf bf16 [E*CAP2][DFF], xg/y aliased bf16 [E*CAP2][DM]
    char* ws = (char*)d_ws;
    size_t off = 0;
    bf16* hbuf = (bf16*)(ws + off); off += (size_t)NEXP * CAP2 * DFF * 2;
    bf16* xg   = (bf16*)(ws + off); off += (size_t)NEXP * CAP2 * DM * 2;
    bf16* y    = xg;  // xg dead after GEMM1; GEMM2 writes y here (stream-ordered)
    int* count   = (int*)(ws + off); off += 256;
    int* slot_of = (int*)(ws + off); off += (size_t)ASSIGN * 4;

    k_zero<<<1, 64, 0, stream>>>(count);
    k_route<<<ASSIGN / 256, 256, 0, stream>>>(cat, sub, count, slot_of);
    k_gather<<<ASSIGN, 64, 0, stream>>>(hidden, slot_of, xg);

    // h = gelu(x @ W1 + b1): per expert M=count[e] (<=512), N=2048, K=512
    dim3 gg1(DFF / BN, CAP2 / BM, NEXP);   // (16, 2, 64)
    k_gemm<true><<<gg1, 512, 0, stream>>>(xg, W1, b1, hbuf, count, DFF, DM);

    // y = h @ W2 + b2: N=512, K=2048
    dim3 gg2(DM / BN, CAP2 / BM, NEXP);    // (4, 2, 64)
    k_gemm<false><<<gg2, 512, 0, stream>>>(hbuf, W2, b2, y, count, DM, DFF);

    k_combine<<<TOKENS, 64, 0, stream>>>(wts, slot_of, y, out);
}